// Round 8
// baseline (375.375 us; speedup 1.0000x reference)
//
#include <hip/hip_runtime.h>

// LSTM forward, fused single kernel. T=2048, B=1024, I=15, H=10 (gate order i,f,g,o).
// One wave per batch row (1024 waves = 1 wave/SIMD, structural; serial over T).
// Lane layout: lane = 4*j + p (j = hidden unit, p = gate i/f/g/o); lanes 40..63 dup j=9.
//
// Pipeline (the round-8 fix): per 16-step block k,
//   - block top: burst-issue x loads for block k+2 into the ping-pong buffer
//   - steps: recurrent chain consumes xacc[] (projected during block k-1);
//            each step also projects ONE x value of block k+1 (from the buffer
//            loaded at block k-1's top -> data ~5000cy old, no vmcnt coupling)
//   - block end: writer-masked burst store of 16 buffered h values
// So the x.Wih projection is fully off the recurrent chain (round 7 had it as a
// chain prefix: +86cy/step), and the inner block stays pure ALU.

#define T_N 2048
#define B_N 1024
#define I_N 15
#define H_N 10
#define DQ  16  // steps per block

typedef _Float16 half2_t __attribute__((ext_vector_type(2)));

template <int CTRL>
static __device__ __forceinline__ float dppf(float v) {
    return __builtin_bit_cast(float,
        __builtin_amdgcn_mov_dpp(__builtin_bit_cast(int, v), CTRL, 0xF, 0xF, true));
}
static __device__ __forceinline__ unsigned rlu(unsigned v, int lane) {
    return (unsigned)__builtin_amdgcn_readlane((int)v, lane);
}
static __device__ __forceinline__ half2_t h2(unsigned u) {
    return __builtin_bit_cast(half2_t, u);
}

// x projection for one timestep (pure ALU, independent of the recurrent chain).
// xv: lane i holds x[t][b][i] (i<15; lane15 dups elem0, killed by wx[7].y=0).
// 3 parallel fdot2 chains (depth<=3) + 2 adds (add3-foldable).
#define PROJ(xv_) ({                                                              \
    const float _xv  = (xv_);                                                     \
    const float _xnb = dppf<0x101>(_xv);               /* lane i reads i+1 */     \
    const unsigned _xpk = __builtin_bit_cast(unsigned,                            \
                              __builtin_amdgcn_cvt_pkrtz(_xv, _xnb));             \
    const unsigned _x0 = rlu(_xpk, 0),  _x1 = rlu(_xpk, 2),  _x2 = rlu(_xpk, 4);  \
    const unsigned _x3 = rlu(_xpk, 6),  _x4 = rlu(_xpk, 8),  _x5 = rlu(_xpk, 10); \
    const unsigned _x6 = rlu(_xpk, 12), _x7 = rlu(_xpk, 14);                      \
    float _a = __builtin_amdgcn_fdot2(h2(_x0), wx[0], 0.f, false);                \
    _a       = __builtin_amdgcn_fdot2(h2(_x1), wx[1], _a,  false);                \
    _a       = __builtin_amdgcn_fdot2(h2(_x2), wx[2], _a,  false);                \
    float _b = __builtin_amdgcn_fdot2(h2(_x3), wx[3], 0.f, false);                \
    _b       = __builtin_amdgcn_fdot2(h2(_x4), wx[4], _b,  false);                \
    _b       = __builtin_amdgcn_fdot2(h2(_x5), wx[5], _b,  false);                \
    float _c = __builtin_amdgcn_fdot2(h2(_x6), wx[6], 0.f, false);                \
    _c       = __builtin_amdgcn_fdot2(h2(_x7), wx[7], _c,  false);                \
    (_a + _b) + _c; })

// one LSTM step: pure ALU. Chain: fdot2(x2)+add3 -> exp2 -> add -> rcp -> fma ->
// dpp -> fma(cs) -> exp2 -> rcp -> fma -> mul -> dpp -> cvt -> readlane.
// Also projects one x value for the NEXT block (off-chain).
#define STEP(d, XACC, XSRC, XACCN) do {                                           \
    const float xav = XACC[d];                                                    \
    float a0 = __builtin_amdgcn_fdot2(h2(hp0), wh[0], xav, false);                \
    a0       = __builtin_amdgcn_fdot2(h2(hp1), wh[1], a0,  false);                \
    float a1 = __builtin_amdgcn_fdot2(h2(hp2), wh[2], 0.f, false);                \
    a1       = __builtin_amdgcn_fdot2(h2(hp3), wh[3], a1,  false);                \
    float a2 = __builtin_amdgcn_fdot2(h2(hp4), wh[4], 0.f, false);                \
    const float acc = (a0 + a1) + a2;                                             \
    const float e   = __builtin_amdgcn_exp2f(acc);                                \
    const float rc  = __builtin_amdgcn_rcpf(1.0f + e);                            \
    const float act = fmaf(Aact, rc, Bact);                                       \
    const float iv = dppf<0x00>(act);                                             \
    const float fv = dppf<0x55>(act);                                             \
    const float gv = dppf<0xAA>(act);   /* pre-scaled by 2log2e */                \
    const float ov = dppf<0xFF>(act);                                             \
    cs = fmaf(fv, cs, iv * gv);         /* cs = 2log2e * c */                     \
    const float tt = __builtin_amdgcn_exp2f(cs);                                  \
    const float th = fmaf(-2.0f, __builtin_amdgcn_rcpf(1.0f + tt), 1.0f);         \
    h = ov * th;                                                                  \
    hbuf[d] = h;                                                                  \
    const float hb = dppf<0x104>(h);    /* lane i reads i+4 */                    \
    const unsigned pk2 = __builtin_bit_cast(unsigned,                             \
                             __builtin_amdgcn_cvt_pkrtz(h, hb));                  \
    hp0 = rlu(pk2, 0); hp1 = rlu(pk2, 8); hp2 = rlu(pk2, 16);                     \
    hp3 = rlu(pk2, 24); hp4 = rlu(pk2, 32);                                       \
    XACCN[d] = PROJ(XSRC[d]);           /* project for next block (off-chain) */  \
} while (0)

// block: burst-load x(block+2) into LOADQ, run DQ pure-ALU steps consuming
// XACC[] and projecting SRCQ -> XACCN, then burst-store the DQ h values.
#define BLOCK(LOADQ, SRCQ, XACC, XACCN, T0) do {                                  \
    _Pragma("unroll")                                                             \
    for (int d = 0; d < DQ; ++d) {                                                \
        int tq = (T0) + 2 * DQ + d; if (tq > T_N - 1) tq = T_N - 1;               \
        LOADQ[d] = xlane[(size_t)tq * (B_N * I_N)];                               \
    }                                                                             \
    __builtin_amdgcn_sched_barrier(0);                                            \
    _Pragma("unroll")                                                             \
    for (int d = 0; d < DQ; ++d) { STEP(d, XACC, SRCQ, XACCN); }                  \
    if (writer) {                                                                 \
        _Pragma("unroll")                                                         \
        for (int d = 0; d < DQ; ++d)                                              \
            out[((size_t)((T0) + d)) * (B_N * H_N) + b * H_N + j] = hbuf[d];      \
    }                                                                             \
} while (0)

__global__ __launch_bounds__(64)
__attribute__((amdgpu_waves_per_eu(1, 1)))
void lstm_all(const float* __restrict__ x, const float* __restrict__ h0,
              const float* __restrict__ c0, const float* __restrict__ Wih,
              const float* __restrict__ Whh, float* __restrict__ out)
{
    const int lane = threadIdx.x;
    const int p = lane & 3;                               // gate: 0=i 1=f 2=g 3=o
    int j = lane >> 2; if (j > H_N - 1) j = H_N - 1;      // lanes 40..63 dup j=9
    const int row = p * H_N + j;                          // W row ([i;f;g;o] x 10)
    const int b = blockIdx.x;
    const bool isTanh = (p == 2);
    const float LOG2E = 1.4426950408889634f;
    // weight prescale: sigmoid rows -log2e; tanh row +2log2e.
    const float sg = isTanh ? 2.0f * LOG2E : -LOG2E;
    // g-gate activation additionally pre-scaled by 2log2e so the carried cell
    // state cs = 2log2e*c feeds exp2 directly: g: act = fma(-4log2e, r, 2log2e).
    const float Aact = isTanh ? -4.0f * LOG2E : 1.0f;
    const float Bact = isTanh ?  2.0f * LOG2E : 0.0f;

    // Wih row prescaled -> f16 pairs (pair 7 = (w14, 0): lane-15 garbage killed)
    half2_t wx[8];
#pragma unroll
    for (int m = 0; m < 7; ++m) {
        half2_t w;
        w[0] = (_Float16)(sg * Wih[row * I_N + 2 * m]);
        w[1] = (_Float16)(sg * Wih[row * I_N + 2 * m + 1]);
        wx[m] = w;
    }
    { half2_t w; w[0] = (_Float16)(sg * Wih[row * I_N + 14]); w[1] = (_Float16)0.0f; wx[7] = w; }

    // Whh row prescaled -> f16 pairs
    half2_t wh[5];
#pragma unroll
    for (int m = 0; m < 5; ++m) {
        half2_t w;
        w[0] = (_Float16)(sg * Whh[row * H_N + 2 * m]);
        w[1] = (_Float16)(sg * Whh[row * H_N + 2 * m + 1]);
        wh[m] = w;
    }

    float cs = c0[b * H_N + j] * (2.0f * LOG2E);   // pre-scaled cell state
    float h  = h0[b * H_N + j];

    // pack h -> f16 pairs at lanes 8m, broadcast 5 SGPRs
    unsigned hp0, hp1, hp2, hp3, hp4;
    {
        const float hb = dppf<0x104>(h);
        const unsigned pk = __builtin_bit_cast(unsigned, __builtin_amdgcn_cvt_pkrtz(h, hb));
        hp0 = rlu(pk, 0); hp1 = rlu(pk, 8); hp2 = rlu(pk, 16);
        hp3 = rlu(pk, 24); hp4 = rlu(pk, 32);
    }

    // x access: lane i<15 carries x[t][b][i]; others dup element 0 (same line)
    const int xk = lane < I_N ? lane : 0;
    const float* xlane = x + (size_t)b * I_N + xk;

    // Pipeline prologue:
    //   bufA := x(block 0); xacc := proj(bufA)   [block 0 ready]
    //   bufB := x(block 1)                        [proj'd during block 0]
    float bufA[DQ], bufB[DQ], xacc[DQ], xaccN[DQ], hbuf[DQ];
#pragma unroll
    for (int d = 0; d < DQ; ++d)
        bufA[d] = xlane[(size_t)d * (B_N * I_N)];
#pragma unroll
    for (int d = 0; d < DQ; ++d)
        xacc[d] = PROJ(bufA[d]);
#pragma unroll
    for (int d = 0; d < DQ; ++d)
        bufB[d] = xlane[(size_t)(DQ + d) * (B_N * I_N)];

    const bool writer = (p == 0) && (lane < 4 * H_N);

    // Invariant at block k: XACC holds proj(block k); buffer parity (k+1)&1
    // holds x(block k+1) (loaded at block k-1 top); block k loads x(block k+2)
    // into parity k&1 and projects x(block k+1) -> XACCN.
    for (int t0 = 0; t0 < T_N; t0 += 2 * DQ) {
        BLOCK(bufA, bufB, xacc, xaccN, t0);        // k even
        BLOCK(bufB, bufA, xaccN, xacc, t0 + DQ);   // k odd
    }

    // final hN, cN appended after out (flat tuple order: out, hN, cN)
    if (writer) {
        const size_t base = (size_t)T_N * B_N * H_N;
        out[base + b * H_N + j] = h;                                         // hN
        out[base + (size_t)B_N * H_N + b * H_N + j] = cs * 0.34657359027997264f; // cN
    }
}

extern "C" void kernel_launch(void* const* d_in, const int* in_sizes, int n_in,
                              void* d_out, int out_size, void* d_ws, size_t ws_size,
                              hipStream_t stream) {
    const float* x   = (const float*)d_in[0];
    const float* h0  = (const float*)d_in[1];
    const float* c0  = (const float*)d_in[2];
    const float* Wih = (const float*)d_in[3];
    const float* Whh = (const float*)d_in[4];
    float* out = (float*)d_out;
    lstm_all<<<dim3(B_N), dim3(64), 0, stream>>>(x, h0, c0, Wih, Whh, out);
}

// Round 9
// 336.489 us; speedup vs baseline: 1.1156x; 1.1156x over previous
//
#include <hip/hip_runtime.h>

// LSTM forward, T=2048, B=1024, I=15, H=10 (PyTorch gate order i,f,g,o).
// Producer/consumer wave specialization, one 128-thread block per batch row:
//   wave 0 (consumer): the serial recurrence, minimal issue (~30 instr/step).
//   wave 1 (producer): x.Wih projection -> double-buffered LDS ring (16 steps/buf).
// Rationale (R6-R8 measurements): single in-order wave => step = chain + issue
// (extra work does NOT hide in chain stalls; R7/R8 regressions were ~1:1 with
// added issue). 2 waves/SIMD restores stall-filling via HW wave switching, so
// the consumer step collapses toward pure chain latency (~300cy measured R6).
// All-f32 math (no f16 pre/h-pack): shorter chain tail + better accuracy.
// Lane layout (consumer): lane = 4*j + p, j = hidden unit, p = gate i/f/g/o;
// lanes 40..63 duplicate j=9 (masked on write). Gate combine via DPP quad_perm.
// Weight prescale: sigmoid rows -log2e, tanh row +2log2e; g-gate activation
// additionally scaled 2log2e so cell state is carried as cs = 2log2e*c and
// feeds exp2 directly. h = ov*tanh(c) = fma(-2ov, rcp(1+2^cs), ov).

#define T_N  2048
#define B_N  1024
#define I_N  15
#define H_N  10
#define DQ   16            // steps per LDS buffer
#define NBLK (T_N / DQ)    // 128 blocks
#define LCOL 40

template <int CTRL>
static __device__ __forceinline__ float dppf(float v) {
    return __builtin_bit_cast(float,
        __builtin_amdgcn_mov_dpp(__builtin_bit_cast(int, v), CTRL, 0xF, 0xF, true));
}
static __device__ __forceinline__ float rl(float v, int lane) {
    return __builtin_bit_cast(float, __builtin_amdgcn_readlane(__builtin_bit_cast(int, v), lane));
}

// ---- producer: project one 16-step block (x values in XR) into buf[PAR] ----
#define PPROJ(XR, PAR) do {                                                       \
    _Pragma("unroll")                                                             \
    for (int d = 0; d < DQ; ++d) {                                                \
        float pa = 0.f, pb = 0.f, pc = 0.f;                                       \
        _Pragma("unroll")                                                         \
        for (int k2 = 0; k2 < 5; ++k2) pa = fmaf(rl(XR[d], k2),      wih[k2],      pa); \
        _Pragma("unroll")                                                         \
        for (int k2 = 0; k2 < 5; ++k2) pb = fmaf(rl(XR[d], k2 + 5),  wih[k2 + 5],  pb); \
        _Pragma("unroll")                                                         \
        for (int k2 = 0; k2 < 5; ++k2) pc = fmaf(rl(XR[d], k2 + 10), wih[k2 + 10], pc); \
        if (lane < LCOL) buf[PAR][d][lane] = (pa + pb) + pc;                      \
    }                                                                             \
} while (0)

// ---- producer: burst-load x for block KB (clamped) into XR ----
#define PLOAD(XR, KB) do {                                                        \
    _Pragma("unroll")                                                             \
    for (int d = 0; d < DQ; ++d) {                                                \
        int tq = (KB) * DQ + d; if (tq > T_N - 1) tq = T_N - 1;                   \
        XR[d] = xlane[(size_t)tq * (B_N * I_N)];                                  \
    }                                                                             \
} while (0)

// ---- consumer: one LSTM step (pure ALU) ----
#define CSTEP(xav, hout) do {                                                     \
    float a0 = (xav);                                                             \
    a0 = fmaf(hs0, wh0, a0); a0 = fmaf(hs1, wh1, a0); a0 = fmaf(hs2, wh2, a0);    \
    a0 = fmaf(hs3, wh3, a0); a0 = fmaf(hs4, wh4, a0);                             \
    float a1 = hs5 * wh5;    a1 = fmaf(hs6, wh6, a1); a1 = fmaf(hs7, wh7, a1);    \
    a1 = fmaf(hs8, wh8, a1); a1 = fmaf(hs9, wh9, a1);                             \
    const float acc = a0 + a1;                                                    \
    const float e   = __builtin_amdgcn_exp2f(acc);                                \
    const float rc  = __builtin_amdgcn_rcpf(1.0f + e);                            \
    const float act = fmaf(Aact, rc, Bact);                                       \
    const float iv  = dppf<0x00>(act);                                            \
    const float fv  = dppf<0x55>(act);                                            \
    const float gv  = dppf<0xAA>(act);   /* pre-scaled by 2log2e */               \
    const float ov  = dppf<0xFF>(act);                                            \
    cs = fmaf(fv, cs, iv * gv);          /* cs = 2log2e * c */                    \
    const float tt   = __builtin_amdgcn_exp2f(cs);                                \
    const float rr   = __builtin_amdgcn_rcpf(1.0f + tt);                          \
    const float ovm2 = -2.0f * ov;       /* off-chain (ov ready early) */         \
    h = fmaf(ovm2, rr, ov);                                                       \
    (hout) = h;                                                                   \
    hs0 = rl(h, 0);  hs1 = rl(h, 4);  hs2 = rl(h, 8);  hs3 = rl(h, 12);           \
    hs4 = rl(h, 16); hs5 = rl(h, 20); hs6 = rl(h, 24); hs7 = rl(h, 28);           \
    hs8 = rl(h, 32); hs9 = rl(h, 36);                                             \
} while (0)

// ---- consumer: one 16-step block: read buf[PAR], store prev h block, run ----
#define CBLOCK(KB, PAR, HFILL, HSTORE, DOSTORE) do {                              \
    float xa[DQ];                                                                 \
    _Pragma("unroll")                                                             \
    for (int d = 0; d < DQ; ++d) xa[d] = buf[PAR][d][crow];                       \
    if ((DOSTORE) && writer) {                                                    \
        _Pragma("unroll")                                                         \
        for (int d = 0; d < DQ; ++d)                                              \
            out[((size_t)(KB - 1) * DQ + d) * (B_N * H_N) + b * H_N + j] = HSTORE[d]; \
    }                                                                             \
    _Pragma("unroll")                                                             \
    for (int d = 0; d < DQ; ++d) CSTEP(xa[d], HFILL[d]);                          \
} while (0)

__global__ __launch_bounds__(128, 2)
void lstm_pc(const float* __restrict__ x, const float* __restrict__ h0,
             const float* __restrict__ c0, const float* __restrict__ Wih,
             const float* __restrict__ Whh, float* __restrict__ out)
{
    __shared__ float buf[2][DQ][LCOL];   // 5.1 KB: double-buffered pre-activations

    const int tid  = threadIdx.x;
    const int wave = tid >> 6;           // 0 = consumer, 1 = producer
    const int lane = tid & 63;
    const int b    = blockIdx.x;
    const float LOG2E = 1.4426950408889634f;

    // ---------------- per-role state (each wave touches only its own) --------
    // producer
    float wih[I_N];
    float xA[DQ], xB[DQ];
    const int xk = lane < I_N ? lane : 0;
    const float* xlane = x + (size_t)b * I_N + xk;
    // consumer
    const int p = lane & 3;
    int j = lane >> 2; if (j > H_N - 1) j = H_N - 1;
    const int crow = p * H_N + j;
    const bool writer = (p == 0) && (lane < 4 * H_N);
    float wh0, wh1, wh2, wh3, wh4, wh5, wh6, wh7, wh8, wh9;
    float cs, h;
    float hs0, hs1, hs2, hs3, hs4, hs5, hs6, hs7, hs8, hs9;
    float hbA[DQ], hbB[DQ];

    if (wave == 1) {
        // producer init: prescaled Wih row for gate g = lane
        const int g = lane < LCOL ? lane : LCOL - 1;
        const bool isTanhG = (g >= 2 * H_N && g < 3 * H_N);
        const float sgp = isTanhG ? 2.0f * LOG2E : -LOG2E;
#pragma unroll
        for (int i = 0; i < I_N; ++i) wih[i] = sgp * Wih[g * I_N + i];
        // prologue: block 0 projected into buf[0]; x for blocks 1,2 staged
        PLOAD(xA, 0);
        PPROJ(xA, 0);
        PLOAD(xB, 1);
        PLOAD(xA, 2);
    } else {
        // consumer init: prescaled Whh row for gate row crow
        const bool isTanh = (p == 2);
        const float sg = isTanh ? 2.0f * LOG2E : -LOG2E;
        const float* wr = Whh + crow * H_N;
        wh0 = sg * wr[0]; wh1 = sg * wr[1]; wh2 = sg * wr[2]; wh3 = sg * wr[3];
        wh4 = sg * wr[4]; wh5 = sg * wr[5]; wh6 = sg * wr[6]; wh7 = sg * wr[7];
        wh8 = sg * wr[8]; wh9 = sg * wr[9];
        cs = c0[b * H_N + j] * (2.0f * LOG2E);
        h  = h0[b * H_N + j];
        hs0 = rl(h, 0);  hs1 = rl(h, 4);  hs2 = rl(h, 8);  hs3 = rl(h, 12);
        hs4 = rl(h, 16); hs5 = rl(h, 20); hs6 = rl(h, 24); hs7 = rl(h, 28);
        hs8 = rl(h, 32); hs9 = rl(h, 36);
    }
    __syncthreads();

    // consumer's act constants (harmless for producer)
    const float Aact = (p == 2) ? -4.0f * LOG2E : 1.0f;
    const float Bact = (p == 2) ?  2.0f * LOG2E : 0.0f;

    // Invariants at even block-step m:
    //   buf[0] holds block m (for consumer); xB holds x of block m+1.
    //   Producer projects m+1 -> buf[1], reloads xB with block m+3.
    for (int m = 0; m < NBLK; m += 2) {
        if (wave == 1) { PPROJ(xB, 1); PLOAD(xB, m + 3); }
        else           { CBLOCK(m, 0, hbA, hbB, m > 0); }
        __syncthreads();
        if (wave == 1) { PPROJ(xA, 0); PLOAD(xA, m + 4); }
        else           { CBLOCK(m + 1, 1, hbB, hbA, 1); }
        __syncthreads();
    }

    // epilogue: last h block (127, in hbB) + hN, cN (flat order: out, hN, cN)
    if (wave == 0 && writer) {
#pragma unroll
        for (int d = 0; d < DQ; ++d)
            out[((size_t)(NBLK - 1) * DQ + d) * (B_N * H_N) + b * H_N + j] = hbB[d];
        const size_t base = (size_t)T_N * B_N * H_N;
        out[base + b * H_N + j] = h;                                          // hN
        out[base + (size_t)B_N * H_N + b * H_N + j] = cs * 0.34657359027997264f; // cN
    }
}

extern "C" void kernel_launch(void* const* d_in, const int* in_sizes, int n_in,
                              void* d_out, int out_size, void* d_ws, size_t ws_size,
                              hipStream_t stream) {
    const float* x   = (const float*)d_in[0];
    const float* h0  = (const float*)d_in[1];
    const float* c0  = (const float*)d_in[2];
    const float* Wih = (const float*)d_in[3];
    const float* Whh = (const float*)d_in[4];
    float* out = (float*)d_out;
    lstm_pc<<<dim3(B_N), dim3(128), 0, stream>>>(x, h0, c0, Wih, Whh, out);
}

// Round 10
// 319.891 us; speedup vs baseline: 1.1734x; 1.0519x over previous
//
#include <hip/hip_runtime.h>

// LSTM forward, T=2048, B=1024, I=15, H=10 (PyTorch gate order i,f,g,o).
// Producer/consumer wave specialization, one 128-thread block per batch row:
//   wave 0 (consumer): serial recurrence, 16-level dependency chain, ~38 instr/step
//   wave 1 (producer): x.Wih projection (f16 fdot2) -> double-buffered LDS ring
// R9 fixes: (1) light barrier (lgkmcnt-only; __syncthreads' vmcnt(0) drain cost
// ~19cy/step), (2) register diet: single xA / single hbuf / DQ=32, launch_bounds
// (128,2) caps 256 VGPR so 2 waves/SIMD fit spill-free, (3) consumer chain 18->16
// levels: f32 dots (five 2-deep FMA chains + add3 tree) straight from readlane
// SGPRs — no f16 h-pack on the chain.
// Lane layout (consumer): lane = 4*j + p, j=hidden unit, p=gate; lanes 40..63 dup
// j=9 (write-masked). Gate combine via DPP quad_perm. Weight prescale: sigmoid
// rows -log2e, tanh row +2log2e; g-gate act additionally scaled 2log2e so cell
// state is carried as cs = 2log2e*c and feeds exp2 directly.
// h = ov*tanh(c) = fma(-2ov, rcp(1+2^cs), ov).

#define T_N  2048
#define B_N  1024
#define I_N  15
#define H_N  10
#define DQ   32            // steps per LDS buffer
#define NBLK (T_N / DQ)    // 64 blocks
#define LPAD 64            // padded LDS row (unconditional producer writes)

typedef _Float16 half2_t __attribute__((ext_vector_type(2)));

template <int CTRL>
static __device__ __forceinline__ float dppf(float v) {
    return __builtin_bit_cast(float,
        __builtin_amdgcn_mov_dpp(__builtin_bit_cast(int, v), CTRL, 0xF, 0xF, true));
}
static __device__ __forceinline__ float rl(float v, int lane) {
    return __builtin_bit_cast(float, __builtin_amdgcn_readlane(__builtin_bit_cast(int, v), lane));
}
static __device__ __forceinline__ unsigned rlu(unsigned v, int lane) {
    return (unsigned)__builtin_amdgcn_readlane((int)v, lane);
}
static __device__ __forceinline__ half2_t h2(unsigned u) {
    return __builtin_bit_cast(half2_t, u);
}

// light barrier: LDS-consistent, does NOT drain vmcnt (stores/loads stay in flight)
#define BAR() asm volatile("s_waitcnt lgkmcnt(0)\n\ts_barrier" ::: "memory")

// ---- producer: burst-load x for block KB (clamped) into XR ----
#define PLOAD(XR, KB) do {                                                        \
    _Pragma("unroll")                                                             \
    for (int d = 0; d < DQ; ++d) {                                                \
        int tq = (KB) * DQ + d; if (tq > T_N - 1) tq = T_N - 1;                   \
        XR[d] = xlane[(size_t)tq * (B_N * I_N)];                                  \
    }                                                                             \
} while (0)

// ---- producer: project one block (x in XR) into buf[PAR]; f16 pack + fdot2 ----
#define PPROJ(XR, PAR) do {                                                       \
    _Pragma("unroll")                                                             \
    for (int d = 0; d < DQ; ++d) {                                                \
        const float xv  = XR[d];                                                  \
        const float xnb = dppf<0x101>(xv);               /* lane i reads i+1 */   \
        const unsigned xpk = __builtin_bit_cast(unsigned,                         \
                                 __builtin_amdgcn_cvt_pkrtz(xv, xnb));            \
        float pa = __builtin_amdgcn_fdot2(h2(rlu(xpk, 0)),  wx[0], 0.f, false);   \
        pa       = __builtin_amdgcn_fdot2(h2(rlu(xpk, 2)),  wx[1], pa,  false);   \
        pa       = __builtin_amdgcn_fdot2(h2(rlu(xpk, 4)),  wx[2], pa,  false);   \
        float pb = __builtin_amdgcn_fdot2(h2(rlu(xpk, 6)),  wx[3], 0.f, false);   \
        pb       = __builtin_amdgcn_fdot2(h2(rlu(xpk, 8)),  wx[4], pb,  false);   \
        pb       = __builtin_amdgcn_fdot2(h2(rlu(xpk, 10)), wx[5], pb,  false);   \
        float pc = __builtin_amdgcn_fdot2(h2(rlu(xpk, 12)), wx[6], 0.f, false);   \
        pc       = __builtin_amdgcn_fdot2(h2(rlu(xpk, 14)), wx[7], pc,  false);   \
        buf[PAR][d][lane] = (pa + pb) + pc;   /* lanes 40..63 land in pad */      \
    }                                                                             \
} while (0)

// ---- consumer: one LSTM step, 16 dependency levels, pure ALU ----
#define CSTEP(xav, hout) do {                                                     \
    float d0 = fmaf(hs0, wh0, (xav)); d0 = fmaf(hs5, wh5, d0);                    \
    float d1 = hs1 * wh1;             d1 = fmaf(hs6, wh6, d1);                    \
    float d2 = hs2 * wh2;             d2 = fmaf(hs7, wh7, d2);                    \
    float d3 = hs3 * wh3;             d3 = fmaf(hs8, wh8, d3);                    \
    float d4 = hs4 * wh4;             d4 = fmaf(hs9, wh9, d4);                    \
    const float acc = (d0 + d1 + d2) + (d3 + d4);     /* add3 + add + add */      \
    const float e   = __builtin_amdgcn_exp2f(acc);                                \
    const float rc  = __builtin_amdgcn_rcpf(1.0f + e);                            \
    const float act = fmaf(Aact, rc, Bact);                                       \
    const float iv  = dppf<0x00>(act);                                            \
    const float fv  = dppf<0x55>(act);                                            \
    const float gv  = dppf<0xAA>(act);   /* pre-scaled by 2log2e */               \
    const float ov  = dppf<0xFF>(act);                                            \
    const float ovm2 = -2.0f * ov;       /* off-chain */                          \
    cs = fmaf(fv, cs, iv * gv);          /* cs = 2log2e * c */                    \
    const float tt = __builtin_amdgcn_exp2f(cs);                                  \
    const float rr = __builtin_amdgcn_rcpf(1.0f + tt);                            \
    h = fmaf(ovm2, rr, ov);                                                       \
    (hout) = h;                                                                   \
    hs0 = rl(h, 0);  hs1 = rl(h, 4);  hs2 = rl(h, 8);  hs3 = rl(h, 12);           \
    hs4 = rl(h, 16); hs5 = rl(h, 20); hs6 = rl(h, 24); hs7 = rl(h, 28);           \
    hs8 = rl(h, 32); hs9 = rl(h, 36);                                             \
} while (0)

// ---- consumer: one block: LDS->reg burst, DQ pure-ALU steps, store burst ----
#define CBLOCK(KB, PAR) do {                                                      \
    float xa[DQ];                                                                 \
    _Pragma("unroll")                                                             \
    for (int d = 0; d < DQ; ++d) xa[d] = buf[PAR][d][crow];                       \
    _Pragma("unroll")                                                             \
    for (int d = 0; d < DQ; ++d) CSTEP(xa[d], hbuf[d]);                           \
    if (writer) {                                                                 \
        _Pragma("unroll")                                                         \
        for (int d = 0; d < DQ; ++d)                                              \
            out[((size_t)(KB) * DQ + d) * (B_N * H_N) + b * H_N + j] = hbuf[d];   \
    }                                                                             \
} while (0)

__global__ __launch_bounds__(128, 2)
void lstm_pc(const float* __restrict__ x, const float* __restrict__ h0,
             const float* __restrict__ c0, const float* __restrict__ Wih,
             const float* __restrict__ Whh, float* __restrict__ out)
{
    __shared__ float buf[2][DQ][LPAD];   // 16 KB, double-buffered pre-activations

    const int tid  = threadIdx.x;
    const int wave = tid >> 6;           // 0 = consumer, 1 = producer
    const int lane = tid & 63;
    const int b    = blockIdx.x;
    const float LOG2E = 1.4426950408889634f;

    // ---- producer state ----
    half2_t wx[8];
    float xA[DQ];
    const int xk = lane < I_N ? lane : 0;
    const float* xlane = x + (size_t)b * I_N + xk;

    // ---- consumer state ----
    const int p = lane & 3;
    int j = lane >> 2; if (j > H_N - 1) j = H_N - 1;
    const int crow = p * H_N + j;
    const bool writer = (wave == 0) && (p == 0) && (lane < 4 * H_N);
    const float Aact = (p == 2) ? -4.0f * LOG2E : 1.0f;
    const float Bact = (p == 2) ?  2.0f * LOG2E : 0.0f;
    float wh0, wh1, wh2, wh3, wh4, wh5, wh6, wh7, wh8, wh9;
    float cs, h;
    float hs0, hs1, hs2, hs3, hs4, hs5, hs6, hs7, hs8, hs9;
    float hbuf[DQ];

    if (wave == 1) {
        // producer init: prescaled Wih row for gate g = lane, packed f16 pairs
        const int g = lane < 4 * H_N ? lane : 4 * H_N - 1;
        const bool isTanhG = (g >= 2 * H_N && g < 3 * H_N);
        const float sgp = isTanhG ? 2.0f * LOG2E : -LOG2E;
#pragma unroll
        for (int m = 0; m < 7; ++m) {
            half2_t w;
            w[0] = (_Float16)(sgp * Wih[g * I_N + 2 * m]);
            w[1] = (_Float16)(sgp * Wih[g * I_N + 2 * m + 1]);
            wx[m] = w;
        }
        { half2_t w; w[0] = (_Float16)(sgp * Wih[g * I_N + 14]); w[1] = (_Float16)0.0f; wx[7] = w; }
        // prologue: project block 0 into buf[0]; stage x(block 1)
        PLOAD(xA, 0);
        PPROJ(xA, 0);
        PLOAD(xA, 1);
    } else {
        // consumer init: prescaled Whh row for gate row crow
        const float sg = (p == 2) ? 2.0f * LOG2E : -LOG2E;
        const float* wr = Whh + crow * H_N;
        wh0 = sg * wr[0]; wh1 = sg * wr[1]; wh2 = sg * wr[2]; wh3 = sg * wr[3];
        wh4 = sg * wr[4]; wh5 = sg * wr[5]; wh6 = sg * wr[6]; wh7 = sg * wr[7];
        wh8 = sg * wr[8]; wh9 = sg * wr[9];
        cs = c0[b * H_N + j] * (2.0f * LOG2E);
        h  = h0[b * H_N + j];
        hs0 = rl(h, 0);  hs1 = rl(h, 4);  hs2 = rl(h, 8);  hs3 = rl(h, 12);
        hs4 = rl(h, 16); hs5 = rl(h, 20); hs6 = rl(h, 24); hs7 = rl(h, 28);
        hs8 = rl(h, 32); hs9 = rl(h, 36);
    }
    BAR();

    // Invariant at iter m: buf[m&1] holds proj(block m); xA holds x(block m+1).
    // Producer projects block m+1 -> buf[(m+1)&1], then reloads xA = x(block m+2).
    for (int m = 0; m < NBLK; ++m) {
        if (wave == 1) {
            PPROJ(xA, (m + 1) & 1);   // garbage proj at m=63 lands in unread buf
            PLOAD(xA, m + 2);         // clamped at tail
        } else {
            CBLOCK(m, m & 1);
        }
        BAR();
    }

    // epilogue: hN, cN appended after out (flat tuple order: out, hN, cN)
    if (writer) {
        const size_t base = (size_t)T_N * B_N * H_N;
        out[base + b * H_N + j] = h;                                          // hN
        out[base + (size_t)B_N * H_N + b * H_N + j] = cs * 0.34657359027997264f; // cN
    }
}

extern "C" void kernel_launch(void* const* d_in, const int* in_sizes, int n_in,
                              void* d_out, int out_size, void* d_ws, size_t ws_size,
                              hipStream_t stream) {
    const float* x   = (const float*)d_in[0];
    const float* h0  = (const float*)d_in[1];
    const float* c0  = (const float*)d_in[2];
    const float* Wih = (const float*)d_in[3];
    const float* Whh = (const float*)d_in[4];
    float* out = (float*)d_out;
    lstm_pc<<<dim3(B_N), dim3(128), 0, stream>>>(x, h0, c0, Wih, Whh, out);
}